// Round 20
// baseline (115.216 us; speedup 1.0000x reference)
//
#include <hip/hip_runtime.h>
#include <math.h>

#define Bb 256
#define Ll 20000
#define WPOOL 3999
#define HEADS 5
#define HDIM 30
#define NB_K1 (Bb*16)       // k1 conv blocks
#define WBBLK 960           // WB build blocks (480*512/256)
#define PADABLK 388         // A k-pad zero blocks (1024*97/256)
#define MKS 4               // MFMA K-split
#define PS2 (Bb*1800)       // one qkv partial slice: [b][s*450+n]

// workspace layout (float offsets)
#define WS_F    0           // 360: F tables
#define WS_BIAS 368
#define WS_G    384         // 900 pair table
#define WS_FBL  1288
#define WS_FBR  2728
#define WS_BBL  4528
#define WS_BBR  4544
#define WS_X    4608                      // B*WPOOL*4 pooled floats [b][p][s]
#define WS_P    (WS_X + Bb*WPOOL*4)       // MKS * PS2 qkv partials
#define WS_A    (WS_P + MKS*PS2)          // A_bf16 [1024][4096] (ushort)
#define WS_WB   (WS_A + 1024*4096/2)      // WB_bf16 [480][4096] (ushort)
// total floats: WS_WB + 480*4096/2 = 9,022,976 (~36.1 MiB)

typedef short short8 __attribute__((ext_vector_type(8)));
typedef float f32x4 __attribute__((ext_vector_type(4)));

__device__ __forceinline__ unsigned short f2bf(float f) {
    unsigned u = __float_as_uint(f);
    return (unsigned short)((u + 0x7FFFu + ((u >> 16) & 1u)) >> 16);
}

// -------- K0: WP-factored conv tables (unchanged) ---------------------------
__device__ __forceinline__ float tbl_entry(const float* __restrict__ WP,
    int t, int d, int i, int kw2min, int kw2max)
{
    if (t >= 4) return 0.f;
    float p[4] = {0.f, 0.f, 0.f, 0.f};
#pragma unroll
    for (int kh = 0; kh < 4; ++kh) {
        int r = i + kh - 1;
        if (r < 0 || r > 3) continue;
        int kh1 = t - r + 1;
        if (kh1 < 0 || kh1 > 3) continue;
        int lo = d - kw2max; if (lo < 0) lo = 0;
        int hi = d - kw2min; if (hi > 9) hi = 9;
        const float* wpa = WP + (kh1 * 10) * 40 + kh * 10;
        for (int kw1 = lo; kw1 <= hi; ++kw1)
            p[kh] += wpa[kw1 * 40 + (d - kw1)];
    }
    return (p[0] + p[1]) + (p[2] + p[3]);
}

__global__ __launch_bounds__(256) void k0_build(const float* __restrict__ w1g,
    const float* __restrict__ b1g, const float* __restrict__ w2g,
    const float* __restrict__ b2g, float* __restrict__ ws)
{
    __shared__ float w1[200], w2[200], b1[5], WP[1600], SB[40], Fsh[360];
    __shared__ float b2v;
    const int tid = threadIdx.x;

    for (int i = tid; i < 200; i += 256) {
        w1[i] = w1g[i];
        w2[i] = w2g[i];
    }
    if (tid < 5) b1[tid] = b1g[tid];
    if (tid == 5) b2v = b2g[0];
    __syncthreads();

    for (int idx = tid; idx < 1600; idx += 256) {
        int a = idx / 40, b = idx % 40;
        float acc = 0.f;
#pragma unroll
        for (int c = 0; c < 5; ++c) acc += w1[a * 5 + c] * w2[b * 5 + c];
        WP[idx] = acc;
    }
    if (tid < 40) {
        float acc = 0.f;
#pragma unroll
        for (int c = 0; c < 5; ++c) acc += b1[c] * w2[tid * 5 + c];
        SB[tid] = acc;
    }
    __syncthreads();

    if (blockIdx.x == 0) {
        for (int idx = tid; idx < 360; idx += 256) {
            int t = idx / 72, d = (idx / 4) % 18, i = idx % 4;
            float v = tbl_entry(WP, t, d, i, 0, 9);
            Fsh[idx] = v;
            ws[WS_F + idx] = v;
        }
        if (tid < 4) {
            int i = tid;
            float acc = b2v;
#pragma unroll
            for (int kh = 0; kh < 4; ++kh) {
                int r = i + kh - 1;
                if (r < 0 || r > 3) continue;
                for (int kw2 = 0; kw2 < 10; ++kw2) acc += SB[kh * 10 + kw2];
            }
            ws[WS_BIAS + i] = acc;
        }
        __syncthreads();
        for (int idx = tid; idx < 900; idx += 256) {
            int p = idx / 36, j = (idx / 4) % 9, i = idx % 4;
            int t0 = p / 5, t1 = p % 5;
            ws[WS_G + idx] = Fsh[(t0 * 18 + 2 * j) * 4 + i]
                           + Fsh[(t1 * 18 + 2 * j + 1) * 4 + i];
        }
    } else {
        int gidx = (blockIdx.x - 1) * 256 + tid;
        if (gidx < 3240) {
            int wslot = gidx / 360, rem = gidx % 360;
            int t = rem / 72, d = (rem / 4) % 18, i = rem % 4;
            bool left = wslot < 4;
            int wloc = left ? wslot : wslot - 4;
            int kw2min = left ? 4 - wloc : 0;
            int kw2max = left ? 9 : 8 - wloc;
            float v = tbl_entry(WP, t, d, i, kw2min, kw2max);
            ws[(left ? WS_FBL + wloc * 360 : WS_FBR + wloc * 360) + rem] = v;
        } else if (gidx < 3276) {
            int bs = gidx - 3240;
            int wslot = bs / 4, i = bs % 4;
            bool left = wslot < 4;
            int wloc = left ? wslot : wslot - 4;
            int kw2min = left ? 4 - wloc : 0;
            int kw2max = left ? 9 : 8 - wloc;
            float acc = b2v;
#pragma unroll
            for (int kh = 0; kh < 4; ++kh) {
                int r = i + kh - 1;
                if (r < 0 || r > 3) continue;
                for (int kw2 = kw2min; kw2 <= kw2max; ++kw2)
                    acc += SB[kh * 10 + kw2];
            }
            ws[(left ? WS_BBL + wloc * 4 : WS_BBR + wloc * 4) + i] = acc;
        }
    }
}

// -------- K1: conv+pool (writes x fp32 AND A bf16) + WB build + A pad -------
__global__ __launch_bounds__(256) void k1_convpool(const int* __restrict__ tokens,
    const float* __restrict__ Wq, const float* __restrict__ Wk,
    const float* __restrict__ Wv, const float* __restrict__ ws_c,
    float* __restrict__ ws)
{
    __shared__ int tok[1280];
    __shared__ float4 Gs[225];
    __shared__ float4 m5[256];
    __shared__ float4 biasS;

    const int tid = threadIdx.x;

    if (blockIdx.x >= NB_K1) {
        int xb = blockIdx.x - NB_K1;
        unsigned short* Au = reinterpret_cast<unsigned short*>(ws + WS_A);
        unsigned short* WBu = reinterpret_cast<unsigned short*>(ws + WS_WB);
        if (xb < WBBLK) {
            int idx = xb * 256 + tid;          // 0..245759
            int n = idx >> 9;                  // 0..479
            int k0 = (idx & 511) * 8;
            unsigned short vals[8];
            if (n < 450) {
                int proj = n / 150, hh = (n % 150) / 30, e = n % 30;
                const float* Wm = (proj == 0) ? Wq : ((proj == 1) ? Wk : Wv);
                const float* base = Wm + (size_t)hh * WPOOL * 30 + e;
#pragma unroll
                for (int j = 0; j < 8; ++j) {
                    int k = k0 + j;
                    vals[j] = (k < WPOOL) ? f2bf(base[(size_t)k * 30]) : (unsigned short)0;
                }
            } else {
#pragma unroll
                for (int j = 0; j < 8; ++j) vals[j] = 0;
            }
            unsigned w0 = (unsigned)vals[0] | ((unsigned)vals[1] << 16);
            unsigned w1 = (unsigned)vals[2] | ((unsigned)vals[3] << 16);
            unsigned w2 = (unsigned)vals[4] | ((unsigned)vals[5] << 16);
            unsigned w3 = (unsigned)vals[6] | ((unsigned)vals[7] << 16);
            *reinterpret_cast<uint4*>(WBu + (size_t)n * 4096 + k0) =
                make_uint4(w0, w1, w2, w3);
        } else {
            int idx = (xb - WBBLK) * 256 + tid;
            if (idx < 1024 * 97) {
                int row = idx / 97;
                int kk = WPOOL + idx % 97;
                Au[(size_t)row * 4096 + kk] = 0;
            }
        }
        return;
    }

    const int b = blockIdx.x >> 4;
    const int chunk = blockIdx.x & 15;
    const int p0 = chunk * 250;
    const int pcnt = min(250, WPOOL - p0);
    const int colBase = 5 * p0 - 8;

    const float4* Gg = reinterpret_cast<const float4*>(ws_c + WS_G);
    for (int j = tid; j < 225; j += 256) Gs[j] = Gg[j];
    if (tid == 0) biasS = *reinterpret_cast<const float4*>(ws_c + WS_BIAS);
    const int* tb = tokens + (size_t)b * Ll;
    for (int j = tid; j < 1280; j += 256) {
        int u = colBase + j;
        tok[j] = (u >= 0 && u < Ll) ? tb[u] : 4;
    }
    __syncthreads();

    if (tid <= pcnt) {
        const int W = 5 * (p0 + tid);
        int tk[22];
#pragma unroll
        for (int m = 0; m < 22; ++m) tk[m] = tok[5 * tid + m];

        float4 mymax;
        const bool isLeft = (chunk == 0 && tid == 0);
        const bool isRight = (W + 4 >= Ll - 5);
        if (!isLeft && !isRight) {
            float4 bias4 = biasS;
            bool first = true;
#pragma unroll
            for (int c = 0; c < 5; ++c) {
                float a0 = bias4.x, a1 = bias4.y, a2 = bias4.z, a3 = bias4.w;
#pragma unroll
                for (int j = 0; j < 9; ++j) {
                    int pc = tk[c + 2 * j] * 5 + tk[c + 2 * j + 1];
                    float4 g = Gs[pc * 9 + j];
                    a0 += g.x; a1 += g.y; a2 += g.z; a3 += g.w;
                }
                if (first) { mymax = make_float4(a0, a1, a2, a3); first = false; }
                else {
                    mymax.x = fmaxf(mymax.x, a0); mymax.y = fmaxf(mymax.y, a1);
                    mymax.z = fmaxf(mymax.z, a2); mymax.w = fmaxf(mymax.w, a3);
                }
            }
        } else {
            bool first = true;
            for (int c = 0; c < 5; ++c) {
                int w = W + c;
                const float* T; const float* Bv;
                if (w < 4)            { T = ws_c + WS_FBL + w * 360;           Bv = ws_c + WS_BBL + 4 * w; }
                else if (w >= Ll - 5) { T = ws_c + WS_FBR + (w - (Ll - 5)) * 360; Bv = ws_c + WS_BBR + 4 * (w - (Ll - 5)); }
                else                  { T = ws_c + WS_F;                        Bv = ws_c + WS_BIAS; }
                float a0 = Bv[0], a1 = Bv[1], a2 = Bv[2], a3 = Bv[3];
                for (int d = 0; d < 18; ++d) {
                    const float* f = T + (size_t)(tk[c + d] * 18 + d) * 4;
                    a0 += f[0]; a1 += f[1]; a2 += f[2]; a3 += f[3];
                }
                if (first) { mymax = make_float4(a0, a1, a2, a3); first = false; }
                else {
                    mymax.x = fmaxf(mymax.x, a0); mymax.y = fmaxf(mymax.y, a1);
                    mymax.z = fmaxf(mymax.z, a2); mymax.w = fmaxf(mymax.w, a3);
                }
            }
        }
        m5[tid] = mymax;
    }
    __syncthreads();

    if (tid < pcnt) {
        float4 a = m5[tid], c = m5[tid + 1];
        a.x = fmaxf(a.x, c.x); a.y = fmaxf(a.y, c.y);
        a.z = fmaxf(a.z, c.z); a.w = fmaxf(a.w, c.w);
        const int k = p0 + tid;
        reinterpret_cast<float4*>(ws + WS_X)[(size_t)b * WPOOL + k] = a;
        unsigned short* Au = reinterpret_cast<unsigned short*>(ws + WS_A);
        Au[(size_t)(b * 4 + 0) * 4096 + k] = f2bf(a.x);
        Au[(size_t)(b * 4 + 1) * 4096 + k] = f2bf(a.y);
        Au[(size_t)(b * 4 + 2) * 4096 + k] = f2bf(a.z);
        Au[(size_t)(b * 4 + 3) * 4096 + k] = f2bf(a.w);
    }
}

// -------- K2 v15: bf16 MFMA GEMM, 1 n-tile/wave, 1920 blocks ----------------
// Grid mg-innermost: 16 mg x 30 ng x 4 ks -> 7.5 blocks/CU = 30 waves/CU
// (5x R19's TLP). Wave = 16x16 m,n tile x K-slice 1024 (32 steps), 1-step
// software pipeline on the two 16B frag loads. B-tile (32 KB) shared by the
// 16 adjacent mg blocks via L2; A re-reads across ng absorbed by L3 (R19
// FETCH stayed at compulsory traffic).
__global__ __launch_bounds__(256) void k2_mfma(const unsigned short* __restrict__ A,
    const unsigned short* __restrict__ WB, float* __restrict__ P)
{
    const int wave = threadIdx.x >> 6;
    const int lane = threadIdx.x & 63;
    const int mg = blockIdx.x & 15;
    const int rest = blockIdx.x >> 4;
    const int ng = rest % 30;
    const int ks = rest / 30;
    const int m0 = (mg * 4 + wave) * 16;
    const int n0 = ng * 16;
    const int kbase = ks * 1024;

    const int lrow = lane & 15;
    const int lk = (lane >> 4) * 8;

    const unsigned short* Ap = A + (size_t)(m0 + lrow) * 4096 + kbase + lk;
    const unsigned short* Bp = WB + (size_t)(n0 + lrow) * 4096 + kbase + lk;

    f32x4 acc = {0.f, 0.f, 0.f, 0.f};

    short8 a_cur = *reinterpret_cast<const short8*>(Ap);
    short8 b_cur = *reinterpret_cast<const short8*>(Bp);
#pragma unroll 8
    for (int step = 0; step < 32; ++step) {
        int nxt = (step + 1 < 32) ? (step + 1) : step;   // clamp (unused-safe)
        short8 a_next = *reinterpret_cast<const short8*>(Ap + nxt * 32);
        short8 b_next = *reinterpret_cast<const short8*>(Bp + nxt * 32);
        acc = __builtin_amdgcn_mfma_f32_16x16x32_bf16(a_cur, b_cur, acc, 0, 0, 0);
        a_cur = a_next;
        b_cur = b_next;
    }

    const int rbase = (lane >> 4) * 4;
    float* Pb = P + (size_t)ks * PS2;
    int col = n0 + lrow;
    if (col < 450) {
#pragma unroll
        for (int r = 0; r < 4; ++r) {
            int m = m0 + rbase + r;
            Pb[(size_t)(m >> 2) * 1800 + (m & 3) * 450 + col] = acc[r];
        }
    }
}

// -------- K3: attention (S=4 causal) + Wo + dense head (MKS=4 reduce) -------
__global__ __launch_bounds__(256) void k3_attn(const float* __restrict__ Wo,
    const float* __restrict__ d1w, const float* __restrict__ d1b,
    const float* __restrict__ d2w, const float* __restrict__ d2b,
    const float* __restrict__ d3w, const float* __restrict__ d3b,
    const float* __restrict__ ws, float* __restrict__ out)
{
    __shared__ float Qs[5][4][30], Ks2[5][4][30], Vs[5][4][30];
    __shared__ float sc[5][4][4];
    __shared__ float ob[4][150];
    __shared__ float hb[120], h1[10], h2[10];
    const int tid = threadIdx.x;
    const int b = blockIdx.x;
    const float* P = ws + WS_P + (size_t)b * 1800;

    for (int idx = tid; idx < 1800; idx += 256) {
        float val = 0.f;
#pragma unroll
        for (int ks = 0; ks < MKS; ++ks)
            val += P[(size_t)ks * PS2 + idx];
        int s = idx / 450, n = idx % 450;
        int proj = n / 150, hh = (n % 150) / 30, e = n % 30;
        if (proj == 0)      Qs[hh][s][e] = val;
        else if (proj == 1) Ks2[hh][s][e] = val;
        else                Vs[hh][s][e] = val;
    }
    __syncthreads();

    if (tid < 80) {
        int hh = tid >> 4, s = (tid >> 2) & 3, t = tid & 3;
        float a = 0.f;
        if (t <= s) {
            for (int e = 0; e < 30; ++e) a += Qs[hh][s][e] * Ks2[hh][t][e];
            a *= (1.0f / sqrtf(30.0f));
        }
        sc[hh][s][t] = a;
    }
    __syncthreads();

    if (tid < 20) {
        int hh = tid / 4, s = tid % 4;
        float m = -1e30f;
        for (int t = 0; t <= s; ++t) m = fmaxf(m, sc[hh][s][t]);
        float ex[4]; float den = 0.f;
        for (int t = 0; t <= s; ++t) { ex[t] = expf(sc[hh][s][t] - m); den += ex[t]; }
        for (int t = 0; t < 4; ++t) sc[hh][s][t] = (t <= s) ? ex[t] / den : 0.f;
    }
    __syncthreads();

    for (int idx = tid; idx < 600; idx += 256) {
        int s = idx / 150, j = idx % 150, hh = j / 30, e = j % 30;
        float a = 0.f;
        for (int t = 0; t < 4; ++t) a += sc[hh][s][t] * Vs[hh][t][e];
        ob[s][j] = a;
    }
    __syncthreads();

    if (tid < 120) {
        int s = tid / 30, e2 = tid % 30;
        float a = 0.f;
        for (int j = 0; j < 150; ++j) a += ob[s][j] * Wo[j * 30 + e2];
        hb[s * 30 + e2] = a;
    }
    __syncthreads();

    if (tid < 10) {
        float a = d1b[tid];
        for (int i = 0; i < 120; ++i) a += hb[i] * d1w[i * 10 + tid];
        h1[tid] = a > 0.f ? a : 0.2f * a;
    }
    __syncthreads();
    if (tid < 10) {
        float a = d2b[tid];
        for (int i = 0; i < 10; ++i) a += h1[i] * d2w[i * 10 + tid];
        h2[tid] = a > 0.f ? a : 0.2f * a;
    }
    __syncthreads();
    if (tid == 0) {
        float a = d3b[0];
        for (int i = 0; i < 10; ++i) a += h2[i] * d3w[i];
        out[b] = 1.f / (1.f + expf(-a));
    }
}

extern "C" void kernel_launch(void* const* d_in, const int* in_sizes, int n_in,
                              void* d_out, int out_size, void* d_ws, size_t ws_size,
                              hipStream_t stream)
{
    const int*   tokens = (const int*)d_in[0];
    const float* c1w = (const float*)d_in[1];
    const float* c1b = (const float*)d_in[2];
    const float* c2w = (const float*)d_in[3];
    const float* c2b = (const float*)d_in[4];
    const float* Wq  = (const float*)d_in[5];
    const float* Wk  = (const float*)d_in[6];
    const float* Wv  = (const float*)d_in[7];
    const float* Wo  = (const float*)d_in[8];
    const float* d1w = (const float*)d_in[9];
    const float* d1b = (const float*)d_in[10];
    const float* d2w = (const float*)d_in[11];
    const float* d2b = (const float*)d_in[12];
    const float* d3w = (const float*)d_in[13];
    const float* d3b = (const float*)d_in[14];
    float* ws = (float*)d_ws;
    float* out = (float*)d_out;

    k0_build<<<14, 256, 0, stream>>>(c1w, c1b, c2w, c2b, ws);
    k1_convpool<<<NB_K1 + WBBLK + PADABLK, 256, 0, stream>>>(tokens, Wq, Wk, Wv, ws, ws);
    k2_mfma<<<16 * 30 * MKS, 256, 0, stream>>>(
        reinterpret_cast<const unsigned short*>(ws + WS_A),
        reinterpret_cast<const unsigned short*>(ws + WS_WB),
        ws + WS_P);
    k3_attn<<<Bb, 256, 0, stream>>>(Wo, d1w, d1b, d2w, d2b, d3w, d3b, ws, out);
}

// Round 21
// 91.251 us; speedup vs baseline: 1.2626x; 1.2626x over previous
//
#include <hip/hip_runtime.h>
#include <math.h>

#define Bb 256
#define Ll 20000
#define WPOOL 3999
#define HEADS 5
#define HDIM 30
#define NB_K1 (Bb*16)       // k1 conv blocks
#define WBBLK 960           // WB build blocks (480*512/256)
#define PADABLK 388         // A k-pad zero blocks (1024*97/256)
#define PS2 (Bb*1800)       // one qkv partial slice: [b][s*450+n]

// workspace layout (float offsets)
#define WS_F    0           // 360: F tables
#define WS_BIAS 368
#define WS_G    384         // 900 pair table
#define WS_FBL  1288
#define WS_FBR  2728
#define WS_BBL  4528
#define WS_BBR  4544
#define WS_X    4608                      // REUSED: P slices 4..7 (x fp32 is dead)
#define WS_P    (WS_X + Bb*WPOOL*4)       // P slices 0..3
#define WS_A    (WS_P + 4*PS2)            // A_bf16 [1024][4096] (ushort)
#define WS_WB   (WS_A + 1024*4096/2)      // WB_bf16 [480][4096] (ushort)
// total floats: WS_WB + 480*4096/2 = 9,022,976 (~36.1 MiB)
// WS_X region holds 4*PS2 = 1,843,200 floats <= Bb*WPOOL*4 = 4,094,976  OK

typedef short short8 __attribute__((ext_vector_type(8)));
typedef float f32x4 __attribute__((ext_vector_type(4)));

__device__ __forceinline__ unsigned short f2bf(float f) {
    unsigned u = __float_as_uint(f);
    return (unsigned short)((u + 0x7FFFu + ((u >> 16) & 1u)) >> 16);
}

// -------- K0: WP-factored conv tables (unchanged) ---------------------------
__device__ __forceinline__ float tbl_entry(const float* __restrict__ WP,
    int t, int d, int i, int kw2min, int kw2max)
{
    if (t >= 4) return 0.f;
    float p[4] = {0.f, 0.f, 0.f, 0.f};
#pragma unroll
    for (int kh = 0; kh < 4; ++kh) {
        int r = i + kh - 1;
        if (r < 0 || r > 3) continue;
        int kh1 = t - r + 1;
        if (kh1 < 0 || kh1 > 3) continue;
        int lo = d - kw2max; if (lo < 0) lo = 0;
        int hi = d - kw2min; if (hi > 9) hi = 9;
        const float* wpa = WP + (kh1 * 10) * 40 + kh * 10;
        for (int kw1 = lo; kw1 <= hi; ++kw1)
            p[kh] += wpa[kw1 * 40 + (d - kw1)];
    }
    return (p[0] + p[1]) + (p[2] + p[3]);
}

__global__ __launch_bounds__(256) void k0_build(const float* __restrict__ w1g,
    const float* __restrict__ b1g, const float* __restrict__ w2g,
    const float* __restrict__ b2g, float* __restrict__ ws)
{
    __shared__ float w1[200], w2[200], b1[5], WP[1600], SB[40], Fsh[360];
    __shared__ float b2v;
    const int tid = threadIdx.x;

    for (int i = tid; i < 200; i += 256) {
        w1[i] = w1g[i];
        w2[i] = w2g[i];
    }
    if (tid < 5) b1[tid] = b1g[tid];
    if (tid == 5) b2v = b2g[0];
    __syncthreads();

    for (int idx = tid; idx < 1600; idx += 256) {
        int a = idx / 40, b = idx % 40;
        float acc = 0.f;
#pragma unroll
        for (int c = 0; c < 5; ++c) acc += w1[a * 5 + c] * w2[b * 5 + c];
        WP[idx] = acc;
    }
    if (tid < 40) {
        float acc = 0.f;
#pragma unroll
        for (int c = 0; c < 5; ++c) acc += b1[c] * w2[tid * 5 + c];
        SB[tid] = acc;
    }
    __syncthreads();

    if (blockIdx.x == 0) {
        for (int idx = tid; idx < 360; idx += 256) {
            int t = idx / 72, d = (idx / 4) % 18, i = idx % 4;
            float v = tbl_entry(WP, t, d, i, 0, 9);
            Fsh[idx] = v;
            ws[WS_F + idx] = v;
        }
        if (tid < 4) {
            int i = tid;
            float acc = b2v;
#pragma unroll
            for (int kh = 0; kh < 4; ++kh) {
                int r = i + kh - 1;
                if (r < 0 || r > 3) continue;
                for (int kw2 = 0; kw2 < 10; ++kw2) acc += SB[kh * 10 + kw2];
            }
            ws[WS_BIAS + i] = acc;
        }
        __syncthreads();
        for (int idx = tid; idx < 900; idx += 256) {
            int p = idx / 36, j = (idx / 4) % 9, i = idx % 4;
            int t0 = p / 5, t1 = p % 5;
            ws[WS_G + idx] = Fsh[(t0 * 18 + 2 * j) * 4 + i]
                           + Fsh[(t1 * 18 + 2 * j + 1) * 4 + i];
        }
    } else {
        int gidx = (blockIdx.x - 1) * 256 + tid;
        if (gidx < 3240) {
            int wslot = gidx / 360, rem = gidx % 360;
            int t = rem / 72, d = (rem / 4) % 18, i = rem % 4;
            bool left = wslot < 4;
            int wloc = left ? wslot : wslot - 4;
            int kw2min = left ? 4 - wloc : 0;
            int kw2max = left ? 9 : 8 - wloc;
            float v = tbl_entry(WP, t, d, i, kw2min, kw2max);
            ws[(left ? WS_FBL + wloc * 360 : WS_FBR + wloc * 360) + rem] = v;
        } else if (gidx < 3276) {
            int bs = gidx - 3240;
            int wslot = bs / 4, i = bs % 4;
            bool left = wslot < 4;
            int wloc = left ? wslot : wslot - 4;
            int kw2min = left ? 4 - wloc : 0;
            int kw2max = left ? 9 : 8 - wloc;
            float acc = b2v;
#pragma unroll
            for (int kh = 0; kh < 4; ++kh) {
                int r = i + kh - 1;
                if (r < 0 || r > 3) continue;
                for (int kw2 = kw2min; kw2 <= kw2max; ++kw2)
                    acc += SB[kh * 10 + kw2];
            }
            ws[(left ? WS_BBL + wloc * 4 : WS_BBR + wloc * 4) + i] = acc;
        }
    }
}

// -------- K1: conv+pool (A bf16 only; fp32 x write dropped) + WB + pad ------
__global__ __launch_bounds__(256) void k1_convpool(const int* __restrict__ tokens,
    const float* __restrict__ Wq, const float* __restrict__ Wk,
    const float* __restrict__ Wv, const float* __restrict__ ws_c,
    float* __restrict__ ws)
{
    __shared__ int tok[1280];
    __shared__ float4 Gs[225];
    __shared__ float4 m5[256];
    __shared__ float4 biasS;

    const int tid = threadIdx.x;

    if (blockIdx.x >= NB_K1) {
        int xb = blockIdx.x - NB_K1;
        unsigned short* Au = reinterpret_cast<unsigned short*>(ws + WS_A);
        unsigned short* WBu = reinterpret_cast<unsigned short*>(ws + WS_WB);
        if (xb < WBBLK) {
            int idx = xb * 256 + tid;          // 0..245759
            int n = idx >> 9;                  // 0..479
            int k0 = (idx & 511) * 8;
            unsigned short vals[8];
            if (n < 450) {
                int proj = n / 150, hh = (n % 150) / 30, e = n % 30;
                const float* Wm = (proj == 0) ? Wq : ((proj == 1) ? Wk : Wv);
                const float* base = Wm + (size_t)hh * WPOOL * 30 + e;
#pragma unroll
                for (int j = 0; j < 8; ++j) {
                    int k = k0 + j;
                    vals[j] = (k < WPOOL) ? f2bf(base[(size_t)k * 30]) : (unsigned short)0;
                }
            } else {
#pragma unroll
                for (int j = 0; j < 8; ++j) vals[j] = 0;
            }
            unsigned w0 = (unsigned)vals[0] | ((unsigned)vals[1] << 16);
            unsigned w1 = (unsigned)vals[2] | ((unsigned)vals[3] << 16);
            unsigned w2 = (unsigned)vals[4] | ((unsigned)vals[5] << 16);
            unsigned w3 = (unsigned)vals[6] | ((unsigned)vals[7] << 16);
            *reinterpret_cast<uint4*>(WBu + (size_t)n * 4096 + k0) =
                make_uint4(w0, w1, w2, w3);
        } else {
            int idx = (xb - WBBLK) * 256 + tid;
            if (idx < 1024 * 97) {
                int row = idx / 97;
                int kk = WPOOL + idx % 97;
                Au[(size_t)row * 4096 + kk] = 0;
            }
        }
        return;
    }

    const int b = blockIdx.x >> 4;
    const int chunk = blockIdx.x & 15;
    const int p0 = chunk * 250;
    const int pcnt = min(250, WPOOL - p0);
    const int colBase = 5 * p0 - 8;

    const float4* Gg = reinterpret_cast<const float4*>(ws_c + WS_G);
    for (int j = tid; j < 225; j += 256) Gs[j] = Gg[j];
    if (tid == 0) biasS = *reinterpret_cast<const float4*>(ws_c + WS_BIAS);
    const int* tb = tokens + (size_t)b * Ll;
    for (int j = tid; j < 1280; j += 256) {
        int u = colBase + j;
        tok[j] = (u >= 0 && u < Ll) ? tb[u] : 4;
    }
    __syncthreads();

    if (tid <= pcnt) {
        const int W = 5 * (p0 + tid);
        int tk[22];
#pragma unroll
        for (int m = 0; m < 22; ++m) tk[m] = tok[5 * tid + m];

        float4 mymax;
        const bool isLeft = (chunk == 0 && tid == 0);
        const bool isRight = (W + 4 >= Ll - 5);
        if (!isLeft && !isRight) {
            float4 bias4 = biasS;
            bool first = true;
#pragma unroll
            for (int c = 0; c < 5; ++c) {
                float a0 = bias4.x, a1 = bias4.y, a2 = bias4.z, a3 = bias4.w;
#pragma unroll
                for (int j = 0; j < 9; ++j) {
                    int pc = tk[c + 2 * j] * 5 + tk[c + 2 * j + 1];
                    float4 g = Gs[pc * 9 + j];
                    a0 += g.x; a1 += g.y; a2 += g.z; a3 += g.w;
                }
                if (first) { mymax = make_float4(a0, a1, a2, a3); first = false; }
                else {
                    mymax.x = fmaxf(mymax.x, a0); mymax.y = fmaxf(mymax.y, a1);
                    mymax.z = fmaxf(mymax.z, a2); mymax.w = fmaxf(mymax.w, a3);
                }
            }
        } else {
            bool first = true;
            for (int c = 0; c < 5; ++c) {
                int w = W + c;
                const float* T; const float* Bv;
                if (w < 4)            { T = ws_c + WS_FBL + w * 360;           Bv = ws_c + WS_BBL + 4 * w; }
                else if (w >= Ll - 5) { T = ws_c + WS_FBR + (w - (Ll - 5)) * 360; Bv = ws_c + WS_BBR + 4 * (w - (Ll - 5)); }
                else                  { T = ws_c + WS_F;                        Bv = ws_c + WS_BIAS; }
                float a0 = Bv[0], a1 = Bv[1], a2 = Bv[2], a3 = Bv[3];
                for (int d = 0; d < 18; ++d) {
                    const float* f = T + (size_t)(tk[c + d] * 18 + d) * 4;
                    a0 += f[0]; a1 += f[1]; a2 += f[2]; a3 += f[3];
                }
                if (first) { mymax = make_float4(a0, a1, a2, a3); first = false; }
                else {
                    mymax.x = fmaxf(mymax.x, a0); mymax.y = fmaxf(mymax.y, a1);
                    mymax.z = fmaxf(mymax.z, a2); mymax.w = fmaxf(mymax.w, a3);
                }
            }
        }
        m5[tid] = mymax;
    }
    __syncthreads();

    if (tid < pcnt) {
        float4 a = m5[tid], c = m5[tid + 1];
        a.x = fmaxf(a.x, c.x); a.y = fmaxf(a.y, c.y);
        a.z = fmaxf(a.z, c.z); a.w = fmaxf(a.w, c.w);
        const int k = p0 + tid;
        unsigned short* Au = reinterpret_cast<unsigned short*>(ws + WS_A);
        Au[(size_t)(b * 4 + 0) * 4096 + k] = f2bf(a.x);
        Au[(size_t)(b * 4 + 1) * 4096 + k] = f2bf(a.y);
        Au[(size_t)(b * 4 + 2) * 4096 + k] = f2bf(a.z);
        Au[(size_t)(b * 4 + 3) * 4096 + k] = f2bf(a.w);
    }
}

// -------- K2 v17: R19 geometry (5 n-tiles/wave) + 8-way K-split -------------
// Grid 16 mg x 6 ng x 8 ks = 768 blocks = exactly 3/CU (no tail round),
// 12 waves/CU. K-slice 512 -> 16 steps/wave. P slices 0..3 at WS_P,
// 4..7 overlay the dead WS_X region.
__global__ __launch_bounds__(256) void k2_mfma(const unsigned short* __restrict__ A,
    const unsigned short* __restrict__ WB, float* __restrict__ P0,
    float* __restrict__ P1)
{
    const int wave = threadIdx.x >> 6;
    const int lane = threadIdx.x & 63;
    const int mg = blockIdx.x & 15;
    const int rest = blockIdx.x >> 4;
    const int ng = rest % 6;
    const int ks = rest / 6;               // 0..7
    const int m0 = (mg * 4 + wave) * 16;
    const int n0 = ng * 80;
    const int kbase = ks * 512;

    const int lrow = lane & 15;
    const int lk = (lane >> 4) * 8;

    const unsigned short* Ap = A + (size_t)(m0 + lrow) * 4096 + kbase + lk;
    const unsigned short* Bp = WB + (size_t)(n0 + lrow) * 4096 + kbase + lk;

    f32x4 acc0 = {0.f, 0.f, 0.f, 0.f};
    f32x4 acc1 = acc0, acc2 = acc0, acc3 = acc0, acc4 = acc0;

#pragma unroll 4
    for (int step = 0; step < 16; ++step) {
        const unsigned short* ap = Ap + step * 32;
        const unsigned short* bp = Bp + step * 32;
        short8 af = *reinterpret_cast<const short8*>(ap);
        short8 b0 = *reinterpret_cast<const short8*>(bp);
        short8 b1 = *reinterpret_cast<const short8*>(bp + (size_t)16 * 4096);
        short8 b2 = *reinterpret_cast<const short8*>(bp + (size_t)32 * 4096);
        short8 b3 = *reinterpret_cast<const short8*>(bp + (size_t)48 * 4096);
        short8 b4 = *reinterpret_cast<const short8*>(bp + (size_t)64 * 4096);
        acc0 = __builtin_amdgcn_mfma_f32_16x16x32_bf16(af, b0, acc0, 0, 0, 0);
        acc1 = __builtin_amdgcn_mfma_f32_16x16x32_bf16(af, b1, acc1, 0, 0, 0);
        acc2 = __builtin_amdgcn_mfma_f32_16x16x32_bf16(af, b2, acc2, 0, 0, 0);
        acc3 = __builtin_amdgcn_mfma_f32_16x16x32_bf16(af, b3, acc3, 0, 0, 0);
        acc4 = __builtin_amdgcn_mfma_f32_16x16x32_bf16(af, b4, acc4, 0, 0, 0);
    }

    const int rbase = (lane >> 4) * 4;
    float* Pb = (ks < 4) ? (P0 + (size_t)ks * PS2) : (P1 + (size_t)(ks - 4) * PS2);
#define STORE(ACC, T) do {                                              \
        int col = n0 + (T) * 16 + lrow;                                 \
        if (col < 450) {                                                \
            _Pragma("unroll")                                           \
            for (int r = 0; r < 4; ++r) {                               \
                int m = m0 + rbase + r;                                 \
                Pb[(size_t)(m >> 2) * 1800 + (m & 3) * 450 + col] = ACC[r]; \
            }                                                           \
        }                                                               \
    } while (0)
    STORE(acc0, 0); STORE(acc1, 1); STORE(acc2, 2); STORE(acc3, 3); STORE(acc4, 4);
#undef STORE
}

// -------- K3: attention + head; sums 4+4 P slices ---------------------------
__global__ __launch_bounds__(256) void k3_attn(const float* __restrict__ Wo,
    const float* __restrict__ d1w, const float* __restrict__ d1b,
    const float* __restrict__ d2w, const float* __restrict__ d2b,
    const float* __restrict__ d3w, const float* __restrict__ d3b,
    const float* __restrict__ ws, float* __restrict__ out)
{
    __shared__ float Qs[5][4][30], Ks2[5][4][30], Vs[5][4][30];
    __shared__ float sc[5][4][4];
    __shared__ float ob[4][150];
    __shared__ float hb[120], h1[10], h2[10];
    const int tid = threadIdx.x;
    const int b = blockIdx.x;
    const float* P0 = ws + WS_P + (size_t)b * 1800;
    const float* P1 = ws + WS_X + (size_t)b * 1800;

    for (int idx = tid; idx < 1800; idx += 256) {
        float val = 0.f;
#pragma unroll
        for (int ks = 0; ks < 4; ++ks)
            val += P0[(size_t)ks * PS2 + idx] + P1[(size_t)ks * PS2 + idx];
        int s = idx / 450, n = idx % 450;
        int proj = n / 150, hh = (n % 150) / 30, e = n % 30;
        if (proj == 0)      Qs[hh][s][e] = val;
        else if (proj == 1) Ks2[hh][s][e] = val;
        else                Vs[hh][s][e] = val;
    }
    __syncthreads();

    if (tid < 80) {
        int hh = tid >> 4, s = (tid >> 2) & 3, t = tid & 3;
        float a = 0.f;
        if (t <= s) {
            for (int e = 0; e < 30; ++e) a += Qs[hh][s][e] * Ks2[hh][t][e];
            a *= (1.0f / sqrtf(30.0f));
        }
        sc[hh][s][t] = a;
    }
    __syncthreads();

    if (tid < 20) {
        int hh = tid / 4, s = tid % 4;
        float m = -1e30f;
        for (int t = 0; t <= s; ++t) m = fmaxf(m, sc[hh][s][t]);
        float ex[4]; float den = 0.f;
        for (int t = 0; t <= s; ++t) { ex[t] = expf(sc[hh][s][t] - m); den += ex[t]; }
        for (int t = 0; t < 4; ++t) sc[hh][s][t] = (t <= s) ? ex[t] / den : 0.f;
    }
    __syncthreads();

    for (int idx = tid; idx < 600; idx += 256) {
        int s = idx / 150, j = idx % 150, hh = j / 30, e = j % 30;
        float a = 0.f;
        for (int t = 0; t < 4; ++t) a += sc[hh][s][t] * Vs[hh][t][e];
        ob[s][j] = a;
    }
    __syncthreads();

    if (tid < 120) {
        int s = tid / 30, e2 = tid % 30;
        float a = 0.f;
        for (int j = 0; j < 150; ++j) a += ob[s][j] * Wo[j * 30 + e2];
        hb[s * 30 + e2] = a;
    }
    __syncthreads();

    if (tid < 10) {
        float a = d1b[tid];
        for (int i = 0; i < 120; ++i) a += hb[i] * d1w[i * 10 + tid];
        h1[tid] = a > 0.f ? a : 0.2f * a;
    }
    __syncthreads();
    if (tid < 10) {
        float a = d2b[tid];
        for (int i = 0; i < 10; ++i) a += h1[i] * d2w[i * 10 + tid];
        h2[tid] = a > 0.f ? a : 0.2f * a;
    }
    __syncthreads();
    if (tid == 0) {
        float a = d3b[0];
        for (int i = 0; i < 10; ++i) a += h2[i] * d3w[i];
        out[b] = 1.f / (1.f + expf(-a));
    }
}

extern "C" void kernel_launch(void* const* d_in, const int* in_sizes, int n_in,
                              void* d_out, int out_size, void* d_ws, size_t ws_size,
                              hipStream_t stream)
{
    const int*   tokens = (const int*)d_in[0];
    const float* c1w = (const float*)d_in[1];
    const float* c1b = (const float*)d_in[2];
    const float* c2w = (const float*)d_in[3];
    const float* c2b = (const float*)d_in[4];
    const float* Wq  = (const float*)d_in[5];
    const float* Wk  = (const float*)d_in[6];
    const float* Wv  = (const float*)d_in[7];
    const float* Wo  = (const float*)d_in[8];
    const float* d1w = (const float*)d_in[9];
    const float* d1b = (const float*)d_in[10];
    const float* d2w = (const float*)d_in[11];
    const float* d2b = (const float*)d_in[12];
    const float* d3w = (const float*)d_in[13];
    const float* d3b = (const float*)d_in[14];
    float* ws = (float*)d_ws;
    float* out = (float*)d_out;

    k0_build<<<14, 256, 0, stream>>>(c1w, c1b, c2w, c2b, ws);
    k1_convpool<<<NB_K1 + WBBLK + PADABLK, 256, 0, stream>>>(tokens, Wq, Wk, Wv, ws, ws);
    k2_mfma<<<16 * 6 * 8, 256, 0, stream>>>(
        reinterpret_cast<const unsigned short*>(ws + WS_A),
        reinterpret_cast<const unsigned short*>(ws + WS_WB),
        ws + WS_P, ws + WS_X);
    k3_attn<<<Bb, 256, 0, stream>>>(Wo, d1w, d1b, d2w, d2b, d3w, d3b, ws, out);
}

// Round 22
// 88.851 us; speedup vs baseline: 1.2967x; 1.0270x over previous
//
#include <hip/hip_runtime.h>
#include <math.h>

#define Bb 256
#define Ll 20000
#define WPOOL 3999
#define HEADS 5
#define HDIM 30
#define NB_K1 (Bb*16)       // k1 conv blocks (pure conv now)
#define WBBLK 960           // WB build blocks (480*512/256)
#define PADABLK 388         // A k-pad zero blocks (1024*97/256)
#define PS2 (Bb*1800)       // one qkv partial slice: [b][s*450+n]

// workspace layout (float offsets)
#define WS_F    0           // 360: F tables
#define WS_BIAS 368
#define WS_G    384         // 900 pair table
#define WS_FBL  1288
#define WS_FBR  2728
#define WS_BBL  4528
#define WS_BBR  4544
#define WS_X    4608                      // REUSED: P slices 4..7
#define WS_P    (WS_X + Bb*WPOOL*4)       // P slices 0..3
#define WS_A    (WS_P + 4*PS2)            // A_bf16 [1024][4096] (ushort)
#define WS_WB   (WS_A + 1024*4096/2)      // WB_bf16 [480][4096] (ushort)
// total floats: WS_WB + 480*4096/2 = 9,022,976 (~36.1 MiB)

typedef short short8 __attribute__((ext_vector_type(8)));
typedef float f32x4 __attribute__((ext_vector_type(4)));

__device__ __forceinline__ unsigned short f2bf(float f) {
    unsigned u = __float_as_uint(f);
    return (unsigned short)((u + 0x7FFFu + ((u >> 16) & 1u)) >> 16);
}

// -------- K0: conv tables (blocks 0..13) + WB build + A pad (blocks 14..) ---
// WB/A-pad work has no dependency on the tables; it runs on the ~242 CUs
// that were idle during the table build, making it effectively free and
// shortening k1's makespan.
__device__ __forceinline__ float tbl_entry(const float* __restrict__ WP,
    int t, int d, int i, int kw2min, int kw2max)
{
    if (t >= 4) return 0.f;
    float p[4] = {0.f, 0.f, 0.f, 0.f};
#pragma unroll
    for (int kh = 0; kh < 4; ++kh) {
        int r = i + kh - 1;
        if (r < 0 || r > 3) continue;
        int kh1 = t - r + 1;
        if (kh1 < 0 || kh1 > 3) continue;
        int lo = d - kw2max; if (lo < 0) lo = 0;
        int hi = d - kw2min; if (hi > 9) hi = 9;
        const float* wpa = WP + (kh1 * 10) * 40 + kh * 10;
        for (int kw1 = lo; kw1 <= hi; ++kw1)
            p[kh] += wpa[kw1 * 40 + (d - kw1)];
    }
    return (p[0] + p[1]) + (p[2] + p[3]);
}

__global__ __launch_bounds__(256) void k0_build(const float* __restrict__ w1g,
    const float* __restrict__ b1g, const float* __restrict__ w2g,
    const float* __restrict__ b2g,
    const float* __restrict__ Wq, const float* __restrict__ Wk,
    const float* __restrict__ Wv, float* __restrict__ ws)
{
    const int tid = threadIdx.x;

    if (blockIdx.x >= 14) {
        int xb = blockIdx.x - 14;
        unsigned short* Au = reinterpret_cast<unsigned short*>(ws + WS_A);
        unsigned short* WBu = reinterpret_cast<unsigned short*>(ws + WS_WB);
        if (xb < WBBLK) {
            int idx = xb * 256 + tid;          // 0..245759
            int n = idx >> 9;                  // 0..479
            int k0 = (idx & 511) * 8;
            unsigned short vals[8];
            if (n < 450) {
                int proj = n / 150, hh = (n % 150) / 30, e = n % 30;
                const float* Wm = (proj == 0) ? Wq : ((proj == 1) ? Wk : Wv);
                const float* base = Wm + (size_t)hh * WPOOL * 30 + e;
#pragma unroll
                for (int j = 0; j < 8; ++j) {
                    int k = k0 + j;
                    vals[j] = (k < WPOOL) ? f2bf(base[(size_t)k * 30]) : (unsigned short)0;
                }
            } else {
#pragma unroll
                for (int j = 0; j < 8; ++j) vals[j] = 0;
            }
            unsigned v0 = (unsigned)vals[0] | ((unsigned)vals[1] << 16);
            unsigned v1 = (unsigned)vals[2] | ((unsigned)vals[3] << 16);
            unsigned v2 = (unsigned)vals[4] | ((unsigned)vals[5] << 16);
            unsigned v3 = (unsigned)vals[6] | ((unsigned)vals[7] << 16);
            *reinterpret_cast<uint4*>(WBu + (size_t)n * 4096 + k0) =
                make_uint4(v0, v1, v2, v3);
        } else {
            int idx = (xb - WBBLK) * 256 + tid;
            if (idx < 1024 * 97) {
                int row = idx / 97;
                int kk = WPOOL + idx % 97;
                Au[(size_t)row * 4096 + kk] = 0;
            }
        }
        return;
    }

    __shared__ float w1[200], w2[200], b1[5], WP[1600], SB[40], Fsh[360];
    __shared__ float b2v;

    for (int i = tid; i < 200; i += 256) {
        w1[i] = w1g[i];
        w2[i] = w2g[i];
    }
    if (tid < 5) b1[tid] = b1g[tid];
    if (tid == 5) b2v = b2g[0];
    __syncthreads();

    for (int idx = tid; idx < 1600; idx += 256) {
        int a = idx / 40, b = idx % 40;
        float acc = 0.f;
#pragma unroll
        for (int c = 0; c < 5; ++c) acc += w1[a * 5 + c] * w2[b * 5 + c];
        WP[idx] = acc;
    }
    if (tid < 40) {
        float acc = 0.f;
#pragma unroll
        for (int c = 0; c < 5; ++c) acc += b1[c] * w2[tid * 5 + c];
        SB[tid] = acc;
    }
    __syncthreads();

    if (blockIdx.x == 0) {
        for (int idx = tid; idx < 360; idx += 256) {
            int t = idx / 72, d = (idx / 4) % 18, i = idx % 4;
            float v = tbl_entry(WP, t, d, i, 0, 9);
            Fsh[idx] = v;
            ws[WS_F + idx] = v;
        }
        if (tid < 4) {
            int i = tid;
            float acc = b2v;
#pragma unroll
            for (int kh = 0; kh < 4; ++kh) {
                int r = i + kh - 1;
                if (r < 0 || r > 3) continue;
                for (int kw2 = 0; kw2 < 10; ++kw2) acc += SB[kh * 10 + kw2];
            }
            ws[WS_BIAS + i] = acc;
        }
        __syncthreads();
        for (int idx = tid; idx < 900; idx += 256) {
            int p = idx / 36, j = (idx / 4) % 9, i = idx % 4;
            int t0 = p / 5, t1 = p % 5;
            ws[WS_G + idx] = Fsh[(t0 * 18 + 2 * j) * 4 + i]
                           + Fsh[(t1 * 18 + 2 * j + 1) * 4 + i];
        }
    } else {
        int gidx = (blockIdx.x - 1) * 256 + tid;
        if (gidx < 3240) {
            int wslot = gidx / 360, rem = gidx % 360;
            int t = rem / 72, d = (rem / 4) % 18, i = rem % 4;
            bool left = wslot < 4;
            int wloc = left ? wslot : wslot - 4;
            int kw2min = left ? 4 - wloc : 0;
            int kw2max = left ? 9 : 8 - wloc;
            float v = tbl_entry(WP, t, d, i, kw2min, kw2max);
            ws[(left ? WS_FBL + wloc * 360 : WS_FBR + wloc * 360) + rem] = v;
        } else if (gidx < 3276) {
            int bs = gidx - 3240;
            int wslot = bs / 4, i = bs % 4;
            bool left = wslot < 4;
            int wloc = left ? wslot : wslot - 4;
            int kw2min = left ? 4 - wloc : 0;
            int kw2max = left ? 9 : 8 - wloc;
            float acc = b2v;
#pragma unroll
            for (int kh = 0; kh < 4; ++kh) {
                int r = i + kh - 1;
                if (r < 0 || r > 3) continue;
                for (int kw2 = kw2min; kw2 <= kw2max; ++kw2)
                    acc += SB[kh * 10 + kw2];
            }
            ws[(left ? WS_BBL + wloc * 4 : WS_BBR + wloc * 4) + i] = acc;
        }
    }
}

// -------- K1: pure conv+pool, writes A bf16 ---------------------------------
__global__ __launch_bounds__(256) void k1_convpool(const int* __restrict__ tokens,
    const float* __restrict__ ws_c, float* __restrict__ ws)
{
    __shared__ int tok[1280];
    __shared__ float4 Gs[225];
    __shared__ float4 m5[256];
    __shared__ float4 biasS;

    const int tid = threadIdx.x;
    const int b = blockIdx.x >> 4;
    const int chunk = blockIdx.x & 15;
    const int p0 = chunk * 250;
    const int pcnt = min(250, WPOOL - p0);
    const int colBase = 5 * p0 - 8;

    const float4* Gg = reinterpret_cast<const float4*>(ws_c + WS_G);
    for (int j = tid; j < 225; j += 256) Gs[j] = Gg[j];
    if (tid == 0) biasS = *reinterpret_cast<const float4*>(ws_c + WS_BIAS);
    const int* tb = tokens + (size_t)b * Ll;
    for (int j = tid; j < 1280; j += 256) {
        int u = colBase + j;
        tok[j] = (u >= 0 && u < Ll) ? tb[u] : 4;
    }
    __syncthreads();

    if (tid <= pcnt) {
        const int W = 5 * (p0 + tid);
        int tk[22];
#pragma unroll
        for (int m = 0; m < 22; ++m) tk[m] = tok[5 * tid + m];

        float4 mymax;
        const bool isLeft = (chunk == 0 && tid == 0);
        const bool isRight = (W + 4 >= Ll - 5);
        if (!isLeft && !isRight) {
            float4 bias4 = biasS;
            bool first = true;
#pragma unroll
            for (int c = 0; c < 5; ++c) {
                float a0 = bias4.x, a1 = bias4.y, a2 = bias4.z, a3 = bias4.w;
#pragma unroll
                for (int j = 0; j < 9; ++j) {
                    int pc = tk[c + 2 * j] * 5 + tk[c + 2 * j + 1];
                    float4 g = Gs[pc * 9 + j];
                    a0 += g.x; a1 += g.y; a2 += g.z; a3 += g.w;
                }
                if (first) { mymax = make_float4(a0, a1, a2, a3); first = false; }
                else {
                    mymax.x = fmaxf(mymax.x, a0); mymax.y = fmaxf(mymax.y, a1);
                    mymax.z = fmaxf(mymax.z, a2); mymax.w = fmaxf(mymax.w, a3);
                }
            }
        } else {
            bool first = true;
            for (int c = 0; c < 5; ++c) {
                int w = W + c;
                const float* T; const float* Bv;
                if (w < 4)            { T = ws_c + WS_FBL + w * 360;           Bv = ws_c + WS_BBL + 4 * w; }
                else if (w >= Ll - 5) { T = ws_c + WS_FBR + (w - (Ll - 5)) * 360; Bv = ws_c + WS_BBR + 4 * (w - (Ll - 5)); }
                else                  { T = ws_c + WS_F;                        Bv = ws_c + WS_BIAS; }
                float a0 = Bv[0], a1 = Bv[1], a2 = Bv[2], a3 = Bv[3];
                for (int d = 0; d < 18; ++d) {
                    const float* f = T + (size_t)(tk[c + d] * 18 + d) * 4;
                    a0 += f[0]; a1 += f[1]; a2 += f[2]; a3 += f[3];
                }
                if (first) { mymax = make_float4(a0, a1, a2, a3); first = false; }
                else {
                    mymax.x = fmaxf(mymax.x, a0); mymax.y = fmaxf(mymax.y, a1);
                    mymax.z = fmaxf(mymax.z, a2); mymax.w = fmaxf(mymax.w, a3);
                }
            }
        }
        m5[tid] = mymax;
    }
    __syncthreads();

    if (tid < pcnt) {
        float4 a = m5[tid], c = m5[tid + 1];
        a.x = fmaxf(a.x, c.x); a.y = fmaxf(a.y, c.y);
        a.z = fmaxf(a.z, c.z); a.w = fmaxf(a.w, c.w);
        const int k = p0 + tid;
        unsigned short* Au = reinterpret_cast<unsigned short*>(ws + WS_A);
        Au[(size_t)(b * 4 + 0) * 4096 + k] = f2bf(a.x);
        Au[(size_t)(b * 4 + 1) * 4096 + k] = f2bf(a.y);
        Au[(size_t)(b * 4 + 2) * 4096 + k] = f2bf(a.z);
        Au[(size_t)(b * 4 + 3) * 4096 + k] = f2bf(a.w);
    }
}

// -------- K2: bf16 MFMA GEMM, 5 n-tiles/wave, 8-way K-split (R21, frozen) ---
__global__ __launch_bounds__(256) void k2_mfma(const unsigned short* __restrict__ A,
    const unsigned short* __restrict__ WB, float* __restrict__ P0,
    float* __restrict__ P1)
{
    const int wave = threadIdx.x >> 6;
    const int lane = threadIdx.x & 63;
    const int mg = blockIdx.x & 15;
    const int rest = blockIdx.x >> 4;
    const int ng = rest % 6;
    const int ks = rest / 6;               // 0..7
    const int m0 = (mg * 4 + wave) * 16;
    const int n0 = ng * 80;
    const int kbase = ks * 512;

    const int lrow = lane & 15;
    const int lk = (lane >> 4) * 8;

    const unsigned short* Ap = A + (size_t)(m0 + lrow) * 4096 + kbase + lk;
    const unsigned short* Bp = WB + (size_t)(n0 + lrow) * 4096 + kbase + lk;

    f32x4 acc0 = {0.f, 0.f, 0.f, 0.f};
    f32x4 acc1 = acc0, acc2 = acc0, acc3 = acc0, acc4 = acc0;

#pragma unroll 4
    for (int step = 0; step < 16; ++step) {
        const unsigned short* ap = Ap + step * 32;
        const unsigned short* bp = Bp + step * 32;
        short8 af = *reinterpret_cast<const short8*>(ap);
        short8 b0 = *reinterpret_cast<const short8*>(bp);
        short8 b1 = *reinterpret_cast<const short8*>(bp + (size_t)16 * 4096);
        short8 b2 = *reinterpret_cast<const short8*>(bp + (size_t)32 * 4096);
        short8 b3 = *reinterpret_cast<const short8*>(bp + (size_t)48 * 4096);
        short8 b4 = *reinterpret_cast<const short8*>(bp + (size_t)64 * 4096);
        acc0 = __builtin_amdgcn_mfma_f32_16x16x32_bf16(af, b0, acc0, 0, 0, 0);
        acc1 = __builtin_amdgcn_mfma_f32_16x16x32_bf16(af, b1, acc1, 0, 0, 0);
        acc2 = __builtin_amdgcn_mfma_f32_16x16x32_bf16(af, b2, acc2, 0, 0, 0);
        acc3 = __builtin_amdgcn_mfma_f32_16x16x32_bf16(af, b3, acc3, 0, 0, 0);
        acc4 = __builtin_amdgcn_mfma_f32_16x16x32_bf16(af, b4, acc4, 0, 0, 0);
    }

    const int rbase = (lane >> 4) * 4;
    float* Pb = (ks < 4) ? (P0 + (size_t)ks * PS2) : (P1 + (size_t)(ks - 4) * PS2);
#define STORE(ACC, T) do {                                              \
        int col = n0 + (T) * 16 + lrow;                                 \
        if (col < 450) {                                                \
            _Pragma("unroll")                                           \
            for (int r = 0; r < 4; ++r) {                               \
                int m = m0 + rbase + r;                                 \
                Pb[(size_t)(m >> 2) * 1800 + (m & 3) * 450 + col] = ACC[r]; \
            }                                                           \
        }                                                               \
    } while (0)
    STORE(acc0, 0); STORE(acc1, 1); STORE(acc2, 2); STORE(acc3, 3); STORE(acc4, 4);
#undef STORE
}

// -------- K3: attention + head; sums 4+4 P slices (R21, frozen) -------------
__global__ __launch_bounds__(256) void k3_attn(const float* __restrict__ Wo,
    const float* __restrict__ d1w, const float* __restrict__ d1b,
    const float* __restrict__ d2w, const float* __restrict__ d2b,
    const float* __restrict__ d3w, const float* __restrict__ d3b,
    const float* __restrict__ ws, float* __restrict__ out)
{
    __shared__ float Qs[5][4][30], Ks2[5][4][30], Vs[5][4][30];
    __shared__ float sc[5][4][4];
    __shared__ float ob[4][150];
    __shared__ float hb[120], h1[10], h2[10];
    const int tid = threadIdx.x;
    const int b = blockIdx.x;
    const float* P0 = ws + WS_P + (size_t)b * 1800;
    const float* P1 = ws + WS_X + (size_t)b * 1800;

    for (int idx = tid; idx < 1800; idx += 256) {
        float val = 0.f;
#pragma unroll
        for (int ks = 0; ks < 4; ++ks)
            val += P0[(size_t)ks * PS2 + idx] + P1[(size_t)ks * PS2 + idx];
        int s = idx / 450, n = idx % 450;
        int proj = n / 150, hh = (n % 150) / 30, e = n % 30;
        if (proj == 0)      Qs[hh][s][e] = val;
        else if (proj == 1) Ks2[hh][s][e] = val;
        else                Vs[hh][s][e] = val;
    }
    __syncthreads();

    if (tid < 80) {
        int hh = tid >> 4, s = (tid >> 2) & 3, t = tid & 3;
        float a = 0.f;
        if (t <= s) {
            for (int e = 0; e < 30; ++e) a += Qs[hh][s][e] * Ks2[hh][t][e];
            a *= (1.0f / sqrtf(30.0f));
        }
        sc[hh][s][t] = a;
    }
    __syncthreads();

    if (tid < 20) {
        int hh = tid / 4, s = tid % 4;
        float m = -1e30f;
        for (int t = 0; t <= s; ++t) m = fmaxf(m, sc[hh][s][t]);
        float ex[4]; float den = 0.f;
        for (int t = 0; t <= s; ++t) { ex[t] = expf(sc[hh][s][t] - m); den += ex[t]; }
        for (int t = 0; t < 4; ++t) sc[hh][s][t] = (t <= s) ? ex[t] / den : 0.f;
    }
    __syncthreads();

    for (int idx = tid; idx < 600; idx += 256) {
        int s = idx / 150, j = idx % 150, hh = j / 30, e = j % 30;
        float a = 0.f;
        for (int t = 0; t < 4; ++t) a += sc[hh][s][t] * Vs[hh][t][e];
        ob[s][j] = a;
    }
    __syncthreads();

    if (tid < 120) {
        int s = tid / 30, e2 = tid % 30;
        float a = 0.f;
        for (int j = 0; j < 150; ++j) a += ob[s][j] * Wo[j * 30 + e2];
        hb[s * 30 + e2] = a;
    }
    __syncthreads();

    if (tid < 10) {
        float a = d1b[tid];
        for (int i = 0; i < 120; ++i) a += hb[i] * d1w[i * 10 + tid];
        h1[tid] = a > 0.f ? a : 0.2f * a;
    }
    __syncthreads();
    if (tid < 10) {
        float a = d2b[tid];
        for (int i = 0; i < 10; ++i) a += h1[i] * d2w[i * 10 + tid];
        h2[tid] = a > 0.f ? a : 0.2f * a;
    }
    __syncthreads();
    if (tid == 0) {
        float a = d3b[0];
        for (int i = 0; i < 10; ++i) a += h2[i] * d3w[i];
        out[b] = 1.f / (1.f + expf(-a));
    }
}

extern "C" void kernel_launch(void* const* d_in, const int* in_sizes, int n_in,
                              void* d_out, int out_size, void* d_ws, size_t ws_size,
                              hipStream_t stream)
{
    const int*   tokens = (const int*)d_in[0];
    const float* c1w = (const float*)d_in[1];
    const float* c1b = (const float*)d_in[2];
    const float* c2w = (const float*)d_in[3];
    const float* c2b = (const float*)d_in[4];
    const float* Wq  = (const float*)d_in[5];
    const float* Wk  = (const float*)d_in[6];
    const float* Wv  = (const float*)d_in[7];
    const float* Wo  = (const float*)d_in[8];
    const float* d1w = (const float*)d_in[9];
    const float* d1b = (const float*)d_in[10];
    const float* d2w = (const float*)d_in[11];
    const float* d2b = (const float*)d_in[12];
    const float* d3w = (const float*)d_in[13];
    const float* d3b = (const float*)d_in[14];
    float* ws = (float*)d_ws;
    float* out = (float*)d_out;

    k0_build<<<14 + WBBLK + PADABLK, 256, 0, stream>>>(c1w, c1b, c2w, c2b,
                                                       Wq, Wk, Wv, ws);
    k1_convpool<<<NB_K1, 256, 0, stream>>>(tokens, ws, ws);
    k2_mfma<<<16 * 6 * 8, 256, 0, stream>>>(
        reinterpret_cast<const unsigned short*>(ws + WS_A),
        reinterpret_cast<const unsigned short*>(ws + WS_WB),
        ws + WS_P, ws + WS_X);
    k3_attn<<<Bb, 256, 0, stream>>>(Wo, d1w, d1b, d2w, d2b, d3w, d3b, ws, out);
}